// Round 7
// baseline (740.146 us; speedup 1.0000x reference)
//
#include <hip/hip_runtime.h>

#define N_ROWS 131072
#define DIM    128
#define QST    4
#define KC     1024
#define BM     256     // rows per workgroup (8 waves x 32 rows)
#define NTH    512
#define PNTH   256
#define NWAVE  8
#define EPS    6e-3f   // certified fp16-split argmin margin
#define FLAGB  (1 << 16)

typedef _Float16 h8  __attribute__((ext_vector_type(8)));
typedef float    fx4 __attribute__((ext_vector_type(4)));

typedef __attribute__((address_space(3))) void lds_void;
typedef const __attribute__((address_space(1))) void glb_void;

#define MFMA16(a, b, c) __builtin_amdgcn_mfma_f32_16x16x32_f16((a), (b), (c), 0, 0, 0)

// packB halfs layout: [q][ch(16)][ctl(4)][kt(4)][hl(2)][lane(64)][j(8)]
// -> each 32 KB chunk stages linearly into LDS.
__global__ void k_prep(const float* __restrict__ cb,
                       double* __restrict__ cvec64, float* __restrict__ cvec32,
                       _Float16* __restrict__ packB) {
  int gid = blockIdx.x * blockDim.x + threadIdx.x;
  if (gid >= QST * KC) return;
  int q = gid >> 10, code = gid & (KC - 1);
  int ch = code >> 6, ctl = (code >> 4) & 3, n = code & 15;
  const float* e = cb + ((size_t)q * KC + code) * DIM;
  double s = 0.0;
  for (int d = 0; d < DIM; d++) {
    float v = e[d];
    s = fma((double)v, (double)v, s);
    int kt = d >> 5, g = (d >> 3) & 3, j = d & 7;
    int lane = g * 16 + n;
    size_t base = ((size_t)q * 16 + ch) * 16384
                + (size_t)((ctl * 4 + kt) * 2) * 512 + lane * 8 + j;
    _Float16 hh = (_Float16)v;
    packB[base]       = hh;                          // hi
    packB[base + 512] = (_Float16)(v - (float)hh);   // lo
  }
  cvec64[q * KC + code] = s;
  cvec32[q * KC + code] = (float)s;
}

__global__ __launch_bounds__(NTH, 4) void k_stage(
    int st, const float* rin, float* rout, const float* __restrict__ x,
    const float* __restrict__ cb,
    const double* __restrict__ cvec64, const float* __restrict__ cvec32,
    const _Float16* __restrict__ packB,
    float* __restrict__ oidx, float* __restrict__ lpart, int final_stage)
{
  extern __shared__ float smem[];
  _Float16* Bl    = (_Float16*)smem;                    // [2][16384] halfs = 64 KB
  int*      idxs  = (int*)(smem + 16384);               // 256 ints
  double*   redd  = (double*)(smem + 16384 + 256);      // 8 doubles (8B aligned)
  int*      redi  = (int*)(smem + 16384 + 256 + 16);    // 8 ints
  float*    redf  = smem + 16384 + 256 + 16 + 8;        // 8 floats
  int*      flags = (int*)(smem + 16384 + 256 + 16 + 8 + 8); // 8 ints

  const int tid = threadIdx.x;
  const int lane = tid & 63, wv = tid >> 6;
  const int tx = tid & 15;
  const size_t rowbase = (size_t)blockIdx.x * BM;

  // ---- A-fragments: 2 rowtiles x 4 ktiles, fp16 hi/lo, straight from global
  h8 ah[2][4], al[2][4];
  #pragma unroll
  for (int rt = 0; rt < 2; rt++) {
    const float* rowp = rin + (rowbase + wv * 32 + rt * 16 + (lane & 15)) * (size_t)DIM
                        + ((lane >> 4) * 8);
    #pragma unroll
    for (int kt = 0; kt < 4; kt++) {
      float4 f0 = *(const float4*)(rowp + kt * 32);
      float4 f1 = *(const float4*)(rowp + kt * 32 + 4);
      float vv[8] = {f0.x, f0.y, f0.z, f0.w, f1.x, f1.y, f1.z, f1.w};
      #pragma unroll
      for (int j = 0; j < 8; j++) {
        _Float16 hh = (_Float16)vv[j];
        ah[rt][kt][j] = hh;
        al[rt][kt][j] = (_Float16)(vv[j] - (float)hh);
      }
    }
  }

  const double*   cq64 = cvec64 + st * KC;
  const float*    cq32 = cvec32 + st * KC;
  const float*    Eq   = cb + (size_t)st * KC * DIM;
  const _Float16* PBq  = packB + (size_t)st * 262144;

  // stage one 32 KB chunk (linear): per wave 4 x (64 lanes x 16 B)
  auto stageB = [&](int ch, int buf) {
    const _Float16* src = PBq + (size_t)ch * 16384 + wv * 2048 + lane * 8;
    _Float16* dst = Bl + buf * 16384 + wv * 2048;   // wave-uniform base
    #pragma unroll
    for (int i = 0; i < 4; i++)
      __builtin_amdgcn_global_load_lds((glb_void*)(src + i * 512),
                                       (lds_void*)(dst + i * 512), 16, 0, 0);
  };

  float b1[8], b2[8];
  int   i1[8];
  #pragma unroll
  for (int i = 0; i < 8; i++) { b1[i] = 3.4e38f; b2[i] = 3.4e38f; i1[i] = 0; }

  const fx4 zero4 = {0.f, 0.f, 0.f, 0.f};

  stageB(0, 0);
  __syncthreads();   // vmcnt(0)+lgkmcnt(0) drain: chunk 0 ready

  #pragma unroll 1
  for (int ch = 0; ch < 16; ch++) {
    if (ch < 15) stageB(ch + 1, (ch + 1) & 1);      // prefetch next chunk

    const _Float16* Bb = Bl + (ch & 1) * 16384;
    fx4 acc[2][4];
    #pragma unroll
    for (int rt = 0; rt < 2; rt++)
      #pragma unroll
      for (int ct = 0; ct < 4; ct++) acc[rt][ct] = zero4;

    #pragma unroll
    for (int kt = 0; kt < 4; kt++) {
      #pragma unroll
      for (int ct = 0; ct < 4; ct++) {
        const _Float16* p = Bb + (size_t)((ct * 4 + kt) * 2) * 512 + lane * 8;
        h8 bh = *(const h8*)p;
        h8 bl = *(const h8*)(p + 512);
        acc[0][ct] = MFMA16(ah[0][kt], bh, acc[0][ct]);
        acc[1][ct] = MFMA16(ah[1][kt], bh, acc[1][ct]);
        acc[0][ct] = MFMA16(al[0][kt], bh, acc[0][ct]);
        acc[1][ct] = MFMA16(al[1][kt], bh, acc[1][ct]);
        acc[0][ct] = MFMA16(ah[0][kt], bl, acc[0][ct]);
        acc[1][ct] = MFMA16(ah[1][kt], bl, acc[1][ct]);
      }
    }

    // ---- scores; per-row top-2. C layout: col=lane&15, row=(lane>>4)*4+reg
    #pragma unroll
    for (int ct = 0; ct < 4; ct++) {
      int code = ch * 64 + ct * 16 + tx;
      float cvv = cq32[code];
      #pragma unroll
      for (int rt = 0; rt < 2; rt++) {
        #pragma unroll
        for (int j = 0; j < 4; j++) {
          float sc = fmaf(-2.f, acc[rt][ct][j], cvv);
          int r = rt * 4 + j;
          if (sc < b1[r]) { b2[r] = b1[r]; b1[r] = sc; i1[r] = code; }
          else            { b2[r] = fminf(b2[r], sc); }
        }
      }
    }
    __syncthreads();   // chunk ch consumed; prefetch (vmcnt) drained
  }

  // ---- cross-lane top-2 reduce over the 16 lanes sharing each row
  #pragma unroll
  for (int m = 1; m < 16; m <<= 1) {
    #pragma unroll
    for (int r = 0; r < 8; r++) {
      float ob1 = __shfl_xor(b1[r], m, 64);
      int   oi1 = __shfl_xor(i1[r], m, 64);
      float ob2 = __shfl_xor(b2[r], m, 64);
      bool take = (ob1 < b1[r]) || (ob1 == b1[r] && oi1 < i1[r]);
      float loser = take ? b1[r] : ob1;
      if (take) { b1[r] = ob1; i1[r] = oi1; }
      b2[r] = fminf(fminf(b2[r], ob2), loser);
    }
  }

  if (tx == 0) {
    int g = lane >> 4;
    #pragma unroll
    for (int rt = 0; rt < 2; rt++)
      #pragma unroll
      for (int j = 0; j < 4; j++) {
        int r = rt * 4 + j;
        int fl = (b2[r] - b1[r] <= EPS) ? FLAGB : 0;
        idxs[wv * 32 + rt * 16 + g * 4 + j] = i1[r] | fl;
      }
  }
  __syncthreads();

  // ---- exact fp64 rescue for uncertain rows (rare); reads codebook rows
  {
    bool pred = (tid < BM) && (idxs[tid] & FLAGB);
    unsigned long long bal = __ballot(pred);
    if (lane == 0) flags[wv] = (bal != 0ull) ? 1 : 0;
  }
  __syncthreads();
  int anyflag = flags[0] | flags[1] | flags[2] | flags[3]
              | flags[4] | flags[5] | flags[6] | flags[7];
  if (anyflag) {
    for (int row = 0; row < BM; row++) {
      if (!(idxs[row] & FLAGB)) continue;          // uniform branch
      const float* rrow = rin + (rowbase + row) * (size_t)DIM;
      double dot[2] = {0.0, 0.0};
      for (int d = 0; d < DIM; d++) {
        double a = (double)rrow[d];                // broadcast load
        #pragma unroll
        for (int c = 0; c < 2; c++)
          dot[c] = fma(a, (double)Eq[(size_t)(tid + c * NTH) * DIM + d], dot[c]);
      }
      double bs = 1e300; int bk = 0;
      #pragma unroll
      for (int c = 0; c < 2; c++) {
        int k = tid + c * NTH;
        double s = fma(-2.0, dot[c], cq64[k]);
        if (s < bs || (s == bs && k < bk)) { bs = s; bk = k; }
      }
      #pragma unroll
      for (int m = 1; m < 64; m <<= 1) {
        double ob = __shfl_xor(bs, m, 64);
        int    ok = __shfl_xor(bk, m, 64);
        if (ob < bs || (ob == bs && ok < bk)) { bs = ob; bk = ok; }
      }
      if (lane == 0) { redd[wv] = bs; redi[wv] = bk; }
      __syncthreads();
      if (tid == 0) {
        double fb = redd[0]; int fk = redi[0];
        #pragma unroll
        for (int w = 1; w < NWAVE; w++) {
          if (redd[w] < fb || (redd[w] == fb && redi[w] < fk)) { fb = redd[w]; fk = redi[w]; }
        }
        idxs[row] = fk;                            // flag cleared
      }
      __syncthreads();
    }
  }

  // ---- fused epilogue, fully coalesced flat writes:
  //      r_new = r_old - E[idx]; loss += (E[idx]-r_old)^2; last stage: out = x - r_new
  {
    float lsum = 0.f;
    #pragma unroll 1
    for (int it = 0; it < 16; it++) {
      int g = it * NTH + tid;
      int row = g >> 5, c4 = g & 31;
      int kidx = idxs[row] & 1023;
      if ((g & 31) == 0) oidx[(rowbase + row) * 4 + st] = (float)kidx;
      float4 ev = *(const float4*)(Eq + (size_t)kidx * DIM + c4 * 4);
      float4 rv = *(const float4*)(rin + (rowbase + row) * (size_t)DIM + c4 * 4);
      float4 dv = make_float4(rv.x - ev.x, rv.y - ev.y, rv.z - ev.z, rv.w - ev.w);
      lsum = fmaf(dv.x, dv.x, lsum);
      lsum = fmaf(dv.y, dv.y, lsum);
      lsum = fmaf(dv.z, dv.z, lsum);
      lsum = fmaf(dv.w, dv.w, lsum);
      float4 wv4 = dv;
      if (final_stage) {
        float4 xv = *(const float4*)(x + (rowbase + row) * (size_t)DIM + c4 * 4);
        wv4 = make_float4(xv.x - dv.x, xv.y - dv.y, xv.z - dv.z, xv.w - dv.w);
      }
      *(float4*)(rout + (rowbase + row) * (size_t)DIM + c4 * 4) = wv4;
    }
    #pragma unroll
    for (int m = 1; m < 64; m <<= 1) lsum += __shfl_xor(lsum, m, 64);
    if (lane == 0) redf[wv] = lsum;
    __syncthreads();
    if (tid == 0) {
      float t = 0.f;
      #pragma unroll
      for (int w = 0; w < NWAVE; w++) t += redf[w];
      lpart[st * (N_ROWS / BM) + blockIdx.x] = t;
    }
  }
}

__global__ void k_loss(const float* __restrict__ part, float* __restrict__ o) {
  __shared__ float red[4];
  int tid = threadIdx.x;
  float s = 0.f;
  for (int i = tid; i < QST * (N_ROWS / BM); i += PNTH) s += part[i];
  #pragma unroll
  for (int m = 1; m < 64; m <<= 1) s += __shfl_xor(s, m, 64);
  if ((tid & 63) == 0) red[tid >> 6] = s;
  __syncthreads();
  if (tid == 0)
    o[0] = (red[0] + red[1] + red[2] + red[3]) *
           (1.25f / ((float)QST * (float)N_ROWS * (float)DIM));
}

extern "C" void kernel_launch(void* const* d_in, const int* in_sizes, int n_in,
                              void* d_out, int out_size, void* d_ws, size_t ws_size,
                              hipStream_t stream) {
  const float* x  = (const float*)d_in[0];
  const float* cb = (const float*)d_in[1];
  float* out = (float*)d_out;
  float* ws  = (float*)d_ws;

  float*    r      = out;                                   // residual in x_q region
  double*   cvec64 = (double*)ws;                           // Q*K fp64 ||E||^2
  float*    cvec32 = (float*)(cvec64 + (size_t)QST * KC);
  float*    part   = cvec32 + (size_t)QST * KC;             // Q*512 partials
  _Float16* packB  = (_Float16*)(part + (size_t)QST * (N_ROWS / BM)); // 4 MB frags

  float* out_loss = out + (size_t)N_ROWS * DIM;
  float* out_idx  = out_loss + 1;

  static const size_t SMEM = (16384 + 256 + 16 + 8 + 8 + 8) * sizeof(float); // 66720 B
  hipFuncSetAttribute(reinterpret_cast<const void*>(k_stage),
                      hipFuncAttributeMaxDynamicSharedMemorySize, (int)SMEM);

  k_prep<<<(QST * KC + PNTH - 1) / PNTH, PNTH, 0, stream>>>(cb, cvec64, cvec32, packB);

  for (int s = 0; s < QST; s++) {
    const float* rin = (s == 0) ? x : r;
    k_stage<<<N_ROWS / BM, NTH, SMEM, stream>>>(s, rin, r, x, cb, cvec64, cvec32,
                                                packB, out_idx, part,
                                                (s == QST - 1) ? 1 : 0);
  }

  k_loss<<<1, PNTH, 0, stream>>>(part, out_loss);
}

// Round 8
// 675.423 us; speedup vs baseline: 1.0958x; 1.0958x over previous
//
#include <hip/hip_runtime.h>

#define N_ROWS 131072
#define DIM    128
#define QST    4
#define KC     1024
#define BM     256     // rows per workgroup (8 waves x 32 rows)
#define NTH    512
#define PNTH   256
#define NWAVE  8
#define NCHUNK 32      // 32 codes per chunk, 16 KB fragments
#define EPS    6e-3f   // certified fp16-split argmin margin
#define FLAGB  (1 << 16)

typedef _Float16 h8  __attribute__((ext_vector_type(8)));
typedef float    fx4 __attribute__((ext_vector_type(4)));

typedef __attribute__((address_space(3))) void lds_void;
typedef const __attribute__((address_space(1))) void glb_void;

#define MFMA16(a, b, c) __builtin_amdgcn_mfma_f32_16x16x32_f16((a), (b), (c), 0, 0, 0)

// packB halfs layout: [q][ch(32)][ctl(2)][kt(4)][hl(2)][lane(64)][j(8)]
// -> each 16 KB chunk stages linearly into LDS.
__global__ void k_prep(const float* __restrict__ cb,
                       double* __restrict__ cvec64, float* __restrict__ cvec32,
                       _Float16* __restrict__ packB) {
  int gid = blockIdx.x * blockDim.x + threadIdx.x;
  if (gid >= QST * KC) return;
  int q = gid >> 10, code = gid & (KC - 1);
  int ch = code >> 5, ctl = (code >> 4) & 1, n = code & 15;
  const float* e = cb + ((size_t)q * KC + code) * DIM;
  double s = 0.0;
  for (int d = 0; d < DIM; d++) {
    float v = e[d];
    s = fma((double)v, (double)v, s);
    int kt = d >> 5, g = (d >> 3) & 3, j = d & 7;
    int lane = g * 16 + n;
    size_t base = ((size_t)q * NCHUNK + ch) * 8192
                + (size_t)((ctl * 4 + kt) * 2) * 512 + lane * 8 + j;
    _Float16 hh = (_Float16)v;
    packB[base]       = hh;                          // hi
    packB[base + 512] = (_Float16)(v - (float)hh);   // lo
  }
  cvec64[q * KC + code] = s;
  cvec32[q * KC + code] = (float)s;
}

__global__ __launch_bounds__(NTH, 4) void k_stage(
    int st, const float* rin, float* rout, const float* __restrict__ x,
    const float* __restrict__ cb,
    const double* __restrict__ cvec64, const float* __restrict__ cvec32,
    const _Float16* __restrict__ packB,
    float* __restrict__ oidx, float* __restrict__ lpart, int final_stage)
{
  extern __shared__ float smem[];
  _Float16* Bl      = (_Float16*)smem;                  // [4][8192] halfs = 64 KB
  float*    cvecL   = smem + 16384;                     // 1024 floats = 4 KB
  int*      idxs    = (int*)(smem + 17408);             // 256 ints
  double*   redd    = (double*)(smem + 17664);          // 8 doubles (8B aligned)
  int*      redi    = (int*)(smem + 17680);             // 8 ints
  float*    redf    = smem + 17688;                     // 8 floats
  int*      flags   = (int*)(smem + 17696);             // 8 ints

  const int tid = threadIdx.x;
  const int lane = tid & 63, wv = tid >> 6;
  const int tx = tid & 15;
  const size_t rowbase = (size_t)blockIdx.x * BM;

  const double*   cq64 = cvec64 + st * KC;
  const float*    cq32 = cvec32 + st * KC;
  const float*    Eq   = cb + (size_t)st * KC * DIM;
  const _Float16* PBq  = packB + (size_t)st * 262144;

  // ---- stage cvec32 into LDS (score reads must NOT touch vmcnt in main loop)
  for (int i = tid; i < KC; i += NTH) cvecL[i] = cq32[i];

  // ---- A-fragments: 2 rowtiles x 4 ktiles, fp16 hi/lo, straight from global
  h8 ah[2][4], al[2][4];
  #pragma unroll
  for (int rt = 0; rt < 2; rt++) {
    const float* rowp = rin + (rowbase + wv * 32 + rt * 16 + (lane & 15)) * (size_t)DIM
                        + ((lane >> 4) * 8);
    #pragma unroll
    for (int kt = 0; kt < 4; kt++) {
      float4 f0 = *(const float4*)(rowp + kt * 32);
      float4 f1 = *(const float4*)(rowp + kt * 32 + 4);
      float vv[8] = {f0.x, f0.y, f0.z, f0.w, f1.x, f1.y, f1.z, f1.w};
      #pragma unroll
      for (int j = 0; j < 8; j++) {
        _Float16 hh = (_Float16)vv[j];
        ah[rt][kt][j] = hh;
        al[rt][kt][j] = (_Float16)(vv[j] - (float)hh);
      }
    }
  }

  // All prologue VMEM/LDS ops retired before the counted-vmcnt pipeline starts.
  asm volatile("s_waitcnt vmcnt(0) lgkmcnt(0)" ::: "memory");

  // stage one 16 KB chunk (linear): per wave 2 x (64 lanes x 16 B)
  auto stageB = [&](int ch, int buf) {
    const _Float16* src = PBq + (size_t)ch * 8192 + wv * 1024 + lane * 8;
    _Float16* dst = Bl + buf * 8192 + wv * 1024;   // wave-uniform base
    #pragma unroll
    for (int i = 0; i < 2; i++)
      __builtin_amdgcn_global_load_lds((glb_void*)(src + i * 512),
                                       (lds_void*)(dst + i * 512), 16, 0, 0);
  };

  float b1[8], b2[8];
  int   i1[8];
  #pragma unroll
  for (int i = 0; i < 8; i++) { b1[i] = 3.4e38f; b2[i] = 3.4e38f; i1[i] = 0; }

  const fx4 zero4 = {0.f, 0.f, 0.f, 0.f};

  // prologue: fill pipeline 3 deep (6 loads in flight per wave)
  stageB(0, 0); stageB(1, 1); stageB(2, 2);

  #pragma unroll 1
  for (int ch = 0; ch < NCHUNK; ch++) {
    // counted waits (T4): own chunk-ch loads done; newer chunks stay in flight
    if (ch < NCHUNK - 2)       asm volatile("s_waitcnt vmcnt(4)" ::: "memory");
    else if (ch == NCHUNK - 2) asm volatile("s_waitcnt vmcnt(2)" ::: "memory");
    else                       asm volatile("s_waitcnt vmcnt(0)" ::: "memory");
    __builtin_amdgcn_s_barrier();       // all waves' ch-loads visible; buf[ch-1] retired
    asm volatile("" ::: "memory");      // pin the stage below the barrier
    if (ch + 3 < NCHUNK) stageB(ch + 3, (ch + 3) & 3);

    const _Float16* Bb = Bl + (ch & 3) * 8192;
    fx4 acc[2][2];
    acc[0][0] = zero4; acc[0][1] = zero4; acc[1][0] = zero4; acc[1][1] = zero4;

    __builtin_amdgcn_s_setprio(1);
    #pragma unroll
    for (int kt = 0; kt < 4; kt++) {
      #pragma unroll
      for (int ct = 0; ct < 2; ct++) {
        const _Float16* p = Bb + (size_t)((ct * 4 + kt) * 2) * 512 + lane * 8;
        h8 bh = *(const h8*)p;
        h8 bl = *(const h8*)(p + 512);
        acc[0][ct] = MFMA16(ah[0][kt], bh, acc[0][ct]);
        acc[1][ct] = MFMA16(ah[1][kt], bh, acc[1][ct]);
        acc[0][ct] = MFMA16(al[0][kt], bh, acc[0][ct]);
        acc[1][ct] = MFMA16(al[1][kt], bh, acc[1][ct]);
        acc[0][ct] = MFMA16(ah[0][kt], bl, acc[0][ct]);
        acc[1][ct] = MFMA16(ah[1][kt], bl, acc[1][ct]);
      }
    }
    __builtin_amdgcn_s_setprio(0);

    // ---- scores; per-row top-2. C layout: col=lane&15, row=(lane>>4)*4+reg
    #pragma unroll
    for (int ct = 0; ct < 2; ct++) {
      int code = ch * 32 + ct * 16 + tx;
      float cvv = cvecL[code];
      #pragma unroll
      for (int rt = 0; rt < 2; rt++) {
        #pragma unroll
        for (int j = 0; j < 4; j++) {
          float sc = fmaf(-2.f, acc[rt][ct][j], cvv);
          int r = rt * 4 + j;
          if (sc < b1[r]) { b2[r] = b1[r]; b1[r] = sc; i1[r] = code; }
          else            { b2[r] = fminf(b2[r], sc); }
        }
      }
    }
  }

  // ---- cross-lane top-2 reduce over the 16 lanes sharing each row
  #pragma unroll
  for (int m = 1; m < 16; m <<= 1) {
    #pragma unroll
    for (int r = 0; r < 8; r++) {
      float ob1 = __shfl_xor(b1[r], m, 64);
      int   oi1 = __shfl_xor(i1[r], m, 64);
      float ob2 = __shfl_xor(b2[r], m, 64);
      bool take = (ob1 < b1[r]) || (ob1 == b1[r] && oi1 < i1[r]);
      float loser = take ? b1[r] : ob1;
      if (take) { b1[r] = ob1; i1[r] = oi1; }
      b2[r] = fminf(fminf(b2[r], ob2), loser);
    }
  }

  if (tx == 0) {
    int g = lane >> 4;
    #pragma unroll
    for (int rt = 0; rt < 2; rt++)
      #pragma unroll
      for (int j = 0; j < 4; j++) {
        int r = rt * 4 + j;
        int fl = (b2[r] - b1[r] <= EPS) ? FLAGB : 0;
        idxs[wv * 32 + rt * 16 + g * 4 + j] = i1[r] | fl;
      }
  }
  __syncthreads();

  // ---- exact fp64 rescue for uncertain rows (rare); reads codebook rows
  {
    bool pred = (tid < BM) && (idxs[tid] & FLAGB);
    unsigned long long bal = __ballot(pred);
    if (lane == 0) flags[wv] = (bal != 0ull) ? 1 : 0;
  }
  __syncthreads();
  int anyflag = flags[0] | flags[1] | flags[2] | flags[3]
              | flags[4] | flags[5] | flags[6] | flags[7];
  if (anyflag) {
    for (int row = 0; row < BM; row++) {
      if (!(idxs[row] & FLAGB)) continue;          // uniform branch
      const float* rrow = rin + (rowbase + row) * (size_t)DIM;
      double dot[2] = {0.0, 0.0};
      for (int d = 0; d < DIM; d++) {
        double a = (double)rrow[d];                // broadcast load
        #pragma unroll
        for (int c = 0; c < 2; c++)
          dot[c] = fma(a, (double)Eq[(size_t)(tid + c * NTH) * DIM + d], dot[c]);
      }
      double bs = 1e300; int bk = 0;
      #pragma unroll
      for (int c = 0; c < 2; c++) {
        int k = tid + c * NTH;
        double s = fma(-2.0, dot[c], cq64[k]);
        if (s < bs || (s == bs && k < bk)) { bs = s; bk = k; }
      }
      #pragma unroll
      for (int m = 1; m < 64; m <<= 1) {
        double ob = __shfl_xor(bs, m, 64);
        int    ok = __shfl_xor(bk, m, 64);
        if (ob < bs || (ob == bs && ok < bk)) { bs = ob; bk = ok; }
      }
      if (lane == 0) { redd[wv] = bs; redi[wv] = bk; }
      __syncthreads();
      if (tid == 0) {
        double fb = redd[0]; int fk = redi[0];
        #pragma unroll
        for (int w = 1; w < NWAVE; w++) {
          if (redd[w] < fb || (redd[w] == fb && redi[w] < fk)) { fb = redd[w]; fk = redi[w]; }
        }
        idxs[row] = fk;                            // flag cleared
      }
      __syncthreads();
    }
  }

  // ---- fused epilogue, fully coalesced flat writes:
  //      r_new = r_old - E[idx]; loss += (E[idx]-r_old)^2; last stage: out = x - r_new
  {
    float lsum = 0.f;
    #pragma unroll 1
    for (int it = 0; it < 16; it++) {
      int g = it * NTH + tid;
      int row = g >> 5, c4 = g & 31;
      int kidx = idxs[row] & 1023;
      if ((g & 31) == 0) oidx[(rowbase + row) * 4 + st] = (float)kidx;
      float4 ev = *(const float4*)(Eq + (size_t)kidx * DIM + c4 * 4);
      float4 rv = *(const float4*)(rin + (rowbase + row) * (size_t)DIM + c4 * 4);
      float4 dv = make_float4(rv.x - ev.x, rv.y - ev.y, rv.z - ev.z, rv.w - ev.w);
      lsum = fmaf(dv.x, dv.x, lsum);
      lsum = fmaf(dv.y, dv.y, lsum);
      lsum = fmaf(dv.z, dv.z, lsum);
      lsum = fmaf(dv.w, dv.w, lsum);
      float4 wv4 = dv;
      if (final_stage) {
        float4 xv = *(const float4*)(x + (rowbase + row) * (size_t)DIM + c4 * 4);
        wv4 = make_float4(xv.x - dv.x, xv.y - dv.y, xv.z - dv.z, xv.w - dv.w);
      }
      *(float4*)(rout + (rowbase + row) * (size_t)DIM + c4 * 4) = wv4;
    }
    #pragma unroll
    for (int m = 1; m < 64; m <<= 1) lsum += __shfl_xor(lsum, m, 64);
    if (lane == 0) redf[wv] = lsum;
    __syncthreads();
    if (tid == 0) {
      float t = 0.f;
      #pragma unroll
      for (int w = 0; w < NWAVE; w++) t += redf[w];
      lpart[st * (N_ROWS / BM) + blockIdx.x] = t;
    }
  }
}

__global__ void k_loss(const float* __restrict__ part, float* __restrict__ o) {
  __shared__ float red[4];
  int tid = threadIdx.x;
  float s = 0.f;
  for (int i = tid; i < QST * (N_ROWS / BM); i += PNTH) s += part[i];
  #pragma unroll
  for (int m = 1; m < 64; m <<= 1) s += __shfl_xor(s, m, 64);
  if ((tid & 63) == 0) red[tid >> 6] = s;
  __syncthreads();
  if (tid == 0)
    o[0] = (red[0] + red[1] + red[2] + red[3]) *
           (1.25f / ((float)QST * (float)N_ROWS * (float)DIM));
}

extern "C" void kernel_launch(void* const* d_in, const int* in_sizes, int n_in,
                              void* d_out, int out_size, void* d_ws, size_t ws_size,
                              hipStream_t stream) {
  const float* x  = (const float*)d_in[0];
  const float* cb = (const float*)d_in[1];
  float* out = (float*)d_out;
  float* ws  = (float*)d_ws;

  float*    r      = out;                                   // residual in x_q region
  double*   cvec64 = (double*)ws;                           // Q*K fp64 ||E||^2
  float*    cvec32 = (float*)(cvec64 + (size_t)QST * KC);
  float*    part   = cvec32 + (size_t)QST * KC;             // Q*512 partials
  _Float16* packB  = (_Float16*)(part + (size_t)QST * (N_ROWS / BM)); // 2 MB frags

  float* out_loss = out + (size_t)N_ROWS * DIM;
  float* out_idx  = out_loss + 1;

  static const size_t SMEM = 17704 * sizeof(float); // 70816 B -> 2 blocks/CU
  hipFuncSetAttribute(reinterpret_cast<const void*>(k_stage),
                      hipFuncAttributeMaxDynamicSharedMemorySize, (int)SMEM);

  k_prep<<<(QST * KC + PNTH - 1) / PNTH, PNTH, 0, stream>>>(cb, cvec64, cvec32, packB);

  for (int s = 0; s < QST; s++) {
    const float* rin = (s == 0) ? x : r;
    k_stage<<<N_ROWS / BM, NTH, SMEM, stream>>>(s, rin, r, x, cb, cvec64, cvec32,
                                                packB, out_idx, part,
                                                (s == QST - 1) ? 1 : 0);
  }

  k_loss<<<1, PNTH, 0, stream>>>(part, out_loss);
}

// Round 9
// 652.276 us; speedup vs baseline: 1.1347x; 1.0355x over previous
//
#include <hip/hip_runtime.h>

#define N_ROWS 131072
#define DIM    128
#define QST    4
#define KC     1024
#define BM     128     // rows per workgroup (4 waves x 32 rows)
#define NTH    256
#define PNTH   256
#define NWAVE  4
#define NCHUNK 64      // 16 codes per chunk, 8 KB fragments
#define EPS    6e-3f   // certified fp16-split argmin margin
#define FLAGB  (1 << 16)

typedef _Float16 h8  __attribute__((ext_vector_type(8)));
typedef float    fx4 __attribute__((ext_vector_type(4)));

typedef __attribute__((address_space(3))) void lds_void;
typedef const __attribute__((address_space(1))) void glb_void;

#define MFMA16(a, b, c) __builtin_amdgcn_mfma_f32_16x16x32_f16((a), (b), (c), 0, 0, 0)

// packB halfs layout: [q][ch(64)][kt(4)][hl(2)][lane(64)][j(8)]
// -> each 8 KB chunk (16 codes) stages linearly into LDS.
__global__ void k_prep(const float* __restrict__ cb,
                       double* __restrict__ cvec64, float* __restrict__ cvec32,
                       _Float16* __restrict__ packB) {
  int gid = blockIdx.x * blockDim.x + threadIdx.x;
  if (gid >= QST * KC) return;
  int q = gid >> 10, code = gid & (KC - 1);
  int ch = code >> 4, n = code & 15;
  const float* e = cb + ((size_t)q * KC + code) * DIM;
  double s = 0.0;
  for (int d = 0; d < DIM; d++) {
    float v = e[d];
    s = fma((double)v, (double)v, s);
    int kt = d >> 5, g = (d >> 3) & 3, j = d & 7;
    int lane = g * 16 + n;
    size_t base = ((size_t)q * NCHUNK + ch) * 4096 + (size_t)kt * 1024 + lane * 8 + j;
    _Float16 hh = (_Float16)v;
    packB[base]       = hh;                          // hi
    packB[base + 512] = (_Float16)(v - (float)hh);   // lo
  }
  cvec64[q * KC + code] = s;
  cvec32[q * KC + code] = (float)s;
}

__global__ __launch_bounds__(NTH, 4) void k_stage(
    int st, const float* rin, float* rout, const float* __restrict__ x,
    const float* __restrict__ cb,
    const double* __restrict__ cvec64, const float* __restrict__ cvec32,
    const _Float16* __restrict__ packB,
    float* __restrict__ oidx, float* __restrict__ lpart, int final_stage)
{
  extern __shared__ float smem[];
  _Float16* Bl      = (_Float16*)smem;                  // [3][4096] halfs = 24 KB
  float*    cvecL   = smem + 6144;                      // 1024 floats = 4 KB
  int*      idxs    = (int*)(smem + 7168);              // 128 ints
  double*   redd    = (double*)(smem + 7296);           // 4 doubles (8B aligned)
  int*      redi    = (int*)(smem + 7304);              // 4 ints
  float*    redf    = smem + 7308;                      // 4 floats
  int*      flags   = (int*)(smem + 7312);              // 4 ints

  const int tid = threadIdx.x;
  const int lane = tid & 63, wv = tid >> 6;
  const int tx = tid & 15;
  const size_t rowbase = (size_t)blockIdx.x * BM;

  const double*   cq64 = cvec64 + st * KC;
  const float*    cq32 = cvec32 + st * KC;
  const float*    Eq   = cb + (size_t)st * KC * DIM;
  const _Float16* PBq  = packB + (size_t)st * 262144;

  // ---- stage cvec32 into LDS (score reads must NOT touch vmcnt in main loop)
  for (int i = tid; i < KC; i += NTH) cvecL[i] = cq32[i];

  // ---- A-fragments: 2 rowtiles x 4 ktiles, fp16 hi/lo, straight from global
  h8 ah[2][4], al[2][4];
  #pragma unroll
  for (int rt = 0; rt < 2; rt++) {
    const float* rowp = rin + (rowbase + wv * 32 + rt * 16 + (lane & 15)) * (size_t)DIM
                        + ((lane >> 4) * 8);
    #pragma unroll
    for (int kt = 0; kt < 4; kt++) {
      float4 f0 = *(const float4*)(rowp + kt * 32);
      float4 f1 = *(const float4*)(rowp + kt * 32 + 4);
      float vv[8] = {f0.x, f0.y, f0.z, f0.w, f1.x, f1.y, f1.z, f1.w};
      #pragma unroll
      for (int j = 0; j < 8; j++) {
        _Float16 hh = (_Float16)vv[j];
        ah[rt][kt][j] = hh;
        al[rt][kt][j] = (_Float16)(vv[j] - (float)hh);
      }
    }
  }

  // All prologue VMEM/LDS ops retired; cvecL visible after the sync.
  asm volatile("s_waitcnt vmcnt(0) lgkmcnt(0)" ::: "memory");
  __syncthreads();

  // stage one 8 KB chunk (linear): per wave 2 x (64 lanes x 16 B)
  auto stageB = [&](int ch, int buf) {
    const _Float16* src = PBq + (size_t)ch * 4096 + wv * 1024 + lane * 8;
    _Float16* dst = Bl + buf * 4096 + wv * 1024;   // wave-uniform base
    #pragma unroll
    for (int i = 0; i < 2; i++)
      __builtin_amdgcn_global_load_lds((glb_void*)(src + i * 512),
                                       (lds_void*)(dst + i * 512), 16, 0, 0);
  };

  float b1[8], b2[8];
  int   i1[8];
  #pragma unroll
  for (int i = 0; i < 8; i++) { b1[i] = 3.4e38f; b2[i] = 3.4e38f; i1[i] = 0; }

  const fx4 zero4 = {0.f, 0.f, 0.f, 0.f};

  // prologue: fill pipeline 2 deep (4 loads in flight per wave)
  stageB(0, 0); stageB(1, 1);

  int buf = 0, bufStage = 2;   // buf = ch%3, bufStage = (ch+2)%3
  #pragma unroll 1
  for (int ch = 0; ch < NCHUNK; ch++) {
    // counted wait (T4): own chunk-ch loads done; chunk ch+1 stays in flight
    if (ch < NCHUNK - 1) asm volatile("s_waitcnt vmcnt(2)" ::: "memory");
    else                 asm volatile("s_waitcnt vmcnt(0)" ::: "memory");
    __builtin_amdgcn_s_barrier();       // all waves' ch-loads visible; buf[(ch-1)%3] retired
    asm volatile("" ::: "memory");      // pin the stage below the barrier
    if (ch + 2 < NCHUNK) stageB(ch + 2, bufStage);

    const _Float16* Bb = Bl + buf * 4096;
    fx4 acc[2];
    acc[0] = zero4; acc[1] = zero4;

    __builtin_amdgcn_s_setprio(1);
    #pragma unroll
    for (int kt = 0; kt < 4; kt++) {
      const _Float16* p = Bb + (size_t)kt * 1024 + lane * 8;
      h8 bh = *(const h8*)p;
      h8 bl = *(const h8*)(p + 512);
      acc[0] = MFMA16(ah[0][kt], bh, acc[0]);
      acc[1] = MFMA16(ah[1][kt], bh, acc[1]);
      acc[0] = MFMA16(al[0][kt], bh, acc[0]);
      acc[1] = MFMA16(al[1][kt], bh, acc[1]);
      acc[0] = MFMA16(ah[0][kt], bl, acc[0]);
      acc[1] = MFMA16(ah[1][kt], bl, acc[1]);
    }
    __builtin_amdgcn_s_setprio(0);

    // ---- scores; per-row top-2. C layout: col=lane&15, row=(lane>>4)*4+reg
    {
      int code = ch * 16 + tx;
      float cvv = cvecL[code];
      #pragma unroll
      for (int rt = 0; rt < 2; rt++) {
        #pragma unroll
        for (int j = 0; j < 4; j++) {
          float sc = fmaf(-2.f, acc[rt][j], cvv);
          int r = rt * 4 + j;
          if (sc < b1[r]) { b2[r] = b1[r]; b1[r] = sc; i1[r] = code; }
          else            { b2[r] = fminf(b2[r], sc); }
        }
      }
    }
    buf = (buf == 2) ? 0 : buf + 1;
    bufStage = (bufStage == 2) ? 0 : bufStage + 1;
  }

  // ---- cross-lane top-2 reduce over the 16 lanes sharing each row
  #pragma unroll
  for (int m = 1; m < 16; m <<= 1) {
    #pragma unroll
    for (int r = 0; r < 8; r++) {
      float ob1 = __shfl_xor(b1[r], m, 64);
      int   oi1 = __shfl_xor(i1[r], m, 64);
      float ob2 = __shfl_xor(b2[r], m, 64);
      bool take = (ob1 < b1[r]) || (ob1 == b1[r] && oi1 < i1[r]);
      float loser = take ? b1[r] : ob1;
      if (take) { b1[r] = ob1; i1[r] = oi1; }
      b2[r] = fminf(fminf(b2[r], ob2), loser);
    }
  }

  if (tx == 0) {
    int g = lane >> 4;
    #pragma unroll
    for (int rt = 0; rt < 2; rt++)
      #pragma unroll
      for (int j = 0; j < 4; j++) {
        int r = rt * 4 + j;
        int fl = (b2[r] - b1[r] <= EPS) ? FLAGB : 0;
        idxs[wv * 32 + rt * 16 + g * 4 + j] = i1[r] | fl;
      }
  }
  __syncthreads();

  // ---- exact fp64 rescue for uncertain rows (rare); reads codebook rows
  {
    bool pred = (tid < BM) && (idxs[tid] & FLAGB);
    unsigned long long bal = __ballot(pred);
    if (lane == 0) flags[wv] = (bal != 0ull) ? 1 : 0;
  }
  __syncthreads();
  int anyflag = flags[0] | flags[1] | flags[2] | flags[3];
  if (anyflag) {
    for (int row = 0; row < BM; row++) {
      if (!(idxs[row] & FLAGB)) continue;          // uniform branch
      const float* rrow = rin + (rowbase + row) * (size_t)DIM;
      double dot[4] = {0.0, 0.0, 0.0, 0.0};
      for (int d = 0; d < DIM; d++) {
        double a = (double)rrow[d];                // broadcast load
        #pragma unroll
        for (int c = 0; c < 4; c++)
          dot[c] = fma(a, (double)Eq[(size_t)(tid + c * NTH) * DIM + d], dot[c]);
      }
      double bs = 1e300; int bk = 0;
      #pragma unroll
      for (int c = 0; c < 4; c++) {
        int k = tid + c * NTH;
        double s = fma(-2.0, dot[c], cq64[k]);
        if (s < bs || (s == bs && k < bk)) { bs = s; bk = k; }
      }
      #pragma unroll
      for (int m = 1; m < 64; m <<= 1) {
        double ob = __shfl_xor(bs, m, 64);
        int    ok = __shfl_xor(bk, m, 64);
        if (ob < bs || (ob == bs && ok < bk)) { bs = ob; bk = ok; }
      }
      if (lane == 0) { redd[wv] = bs; redi[wv] = bk; }
      __syncthreads();
      if (tid == 0) {
        double fb = redd[0]; int fk = redi[0];
        #pragma unroll
        for (int w = 1; w < NWAVE; w++) {
          if (redd[w] < fb || (redd[w] == fb && redi[w] < fk)) { fb = redd[w]; fk = redi[w]; }
        }
        idxs[row] = fk;                            // flag cleared
      }
      __syncthreads();
    }
  }

  // ---- fused epilogue, fully coalesced flat writes:
  //      r_new = r_old - E[idx]; loss += (E[idx]-r_old)^2; last stage: out = x - r_new
  {
    float lsum = 0.f;
    #pragma unroll 1
    for (int it = 0; it < 16; it++) {
      int g = it * NTH + tid;
      int row = g >> 5, c4 = g & 31;
      int kidx = idxs[row] & 1023;
      if ((g & 31) == 0) oidx[(rowbase + row) * 4 + st] = (float)kidx;
      float4 ev = *(const float4*)(Eq + (size_t)kidx * DIM + c4 * 4);
      float4 rv = *(const float4*)(rin + (rowbase + row) * (size_t)DIM + c4 * 4);
      float4 dv = make_float4(rv.x - ev.x, rv.y - ev.y, rv.z - ev.z, rv.w - ev.w);
      lsum = fmaf(dv.x, dv.x, lsum);
      lsum = fmaf(dv.y, dv.y, lsum);
      lsum = fmaf(dv.z, dv.z, lsum);
      lsum = fmaf(dv.w, dv.w, lsum);
      float4 wv4 = dv;
      if (final_stage) {
        float4 xv = *(const float4*)(x + (rowbase + row) * (size_t)DIM + c4 * 4);
        wv4 = make_float4(xv.x - dv.x, xv.y - dv.y, xv.z - dv.z, xv.w - dv.w);
      }
      *(float4*)(rout + (rowbase + row) * (size_t)DIM + c4 * 4) = wv4;
    }
    #pragma unroll
    for (int m = 1; m < 64; m <<= 1) lsum += __shfl_xor(lsum, m, 64);
    if (lane == 0) redf[wv] = lsum;
    __syncthreads();
    if (tid == 0) {
      float t = 0.f;
      #pragma unroll
      for (int w = 0; w < NWAVE; w++) t += redf[w];
      lpart[st * (N_ROWS / BM) + blockIdx.x] = t;
    }
  }
}

__global__ void k_loss(const float* __restrict__ part, float* __restrict__ o) {
  __shared__ float red[4];
  int tid = threadIdx.x;
  float s = 0.f;
  for (int i = tid; i < QST * (N_ROWS / BM); i += PNTH) s += part[i];
  #pragma unroll
  for (int m = 1; m < 64; m <<= 1) s += __shfl_xor(s, m, 64);
  if ((tid & 63) == 0) red[tid >> 6] = s;
  __syncthreads();
  if (tid == 0)
    o[0] = (red[0] + red[1] + red[2] + red[3]) *
           (1.25f / ((float)QST * (float)N_ROWS * (float)DIM));
}

extern "C" void kernel_launch(void* const* d_in, const int* in_sizes, int n_in,
                              void* d_out, int out_size, void* d_ws, size_t ws_size,
                              hipStream_t stream) {
  const float* x  = (const float*)d_in[0];
  const float* cb = (const float*)d_in[1];
  float* out = (float*)d_out;
  float* ws  = (float*)d_ws;

  float*    r      = out;                                   // residual in x_q region
  double*   cvec64 = (double*)ws;                           // Q*K fp64 ||E||^2
  float*    cvec32 = (float*)(cvec64 + (size_t)QST * KC);
  float*    part   = cvec32 + (size_t)QST * KC;             // Q*1024 partials
  _Float16* packB  = (_Float16*)(part + (size_t)QST * (N_ROWS / BM)); // 2 MB frags

  float* out_loss = out + (size_t)N_ROWS * DIM;
  float* out_idx  = out_loss + 1;

  static const size_t SMEM = 7316 * sizeof(float); // 29264 B -> >=4 blocks/CU
  hipFuncSetAttribute(reinterpret_cast<const void*>(k_stage),
                      hipFuncAttributeMaxDynamicSharedMemorySize, (int)SMEM);

  k_prep<<<(QST * KC + PNTH - 1) / PNTH, PNTH, 0, stream>>>(cb, cvec64, cvec32, packB);

  for (int s = 0; s < QST; s++) {
    const float* rin = (s == 0) ? x : r;
    k_stage<<<N_ROWS / BM, NTH, SMEM, stream>>>(s, rin, r, x, cb, cvec64, cvec32,
                                                packB, out_idx, part,
                                                (s == QST - 1) ? 1 : 0);
  }

  k_loss<<<1, PNTH, 0, stream>>>(part, out_loss);
}